// Round 1
// baseline (988.579 us; speedup 1.0000x reference)
//
#include <hip/hip_runtime.h>
#include <math.h>

#define SS 65536               // F*T
#define PLANE 4194304          // CC*SS floats per (b,part)
#define TEN_ELEMS 16777216     // 2*2*CC*SS floats per tensor
#define NBUCKET 64

typedef __bf16 bf16x8 __attribute__((ext_vector_type(8)));
typedef __bf16 bf16x4v __attribute__((ext_vector_type(4)));
typedef float  f32x4  __attribute__((ext_vector_type(4)));

__device__ inline f32x4 mfma16(bf16x8 a, bf16x8 b, f32x4 c) {
  return __builtin_amdgcn_mfma_f32_16x16x32_bf16(a, b, c, 0, 0, 0);
}
__device__ inline bf16x8 neg8(bf16x8 v) {
  union { bf16x8 b; unsigned u[4]; } t; t.b = v;
#pragma unroll
  for (int i = 0; i < 4; ++i) t.u[i] ^= 0x80008000u;
  return t.b;
}

// ============ complex 1x1 conv (split-bf16 MFMA) + bias + BN stats ==========
__global__ __launch_bounds__(256) void cconv_mfma(
    const float* __restrict__ x, const float* __restrict__ Wj,
    const float* __restrict__ bias, float* __restrict__ y,
    float* __restrict__ part)
{
  __shared__ __align__(16) __bf16 sBh[64 * 136];   // [s][pc] hi
  __shared__ __align__(16) __bf16 sBl[64 * 136];   // [s][pc] lo
  const int tid = threadIdx.x;
  const int b = blockIdx.y;
  const int s0 = blockIdx.x << 6;
  const int bkt = (blockIdx.x & (NBUCKET - 1)) * 768;
  const int w = tid >> 6, q = (tid >> 4) & 3, ln = tid & 15;

  bf16x8 ah[2][4], al[2][4];
#pragma unroll
  for (int mt = 0; mt < 2; ++mt) {
    int row = w * 32 + mt * 16 + ln;
    int po = row >> 6, co = row & 63;
#pragma unroll
    for (int ks = 0; ks < 4; ++ks) {
      bf16x8 vh, vl;
#pragma unroll
      for (int j = 0; j < 8; ++j) {
        int k = ks * 32 + q * 8 + j;
        int pi = k >> 6, c = k & 63;
        float v = Wj[((po ^ pi) << 12) + co * 64 + c];
        if (po == 0 && pi == 1) v = -v;
        __bf16 h = (__bf16)v;
        vh[j] = h;
        vl[j] = (__bf16)(v - (float)h);
      }
      ah[mt][ks] = vh; al[mt][ks] = vl;
    }
  }

#pragma unroll
  for (int ph = 0; ph < 2; ++ph) {
    int pc = ph * 64 + (tid & 63);
    const float* rowp = x + (size_t)(b * 128 + pc) * SS + s0;
#pragma unroll
    for (int sh2 = 0; sh2 < 2; ++sh2)
#pragma unroll
      for (int sc2 = 0; sc2 < 2; ++sc2) {
        int sl = ((tid >> 6) << 3) + sh2 * 32 + sc2 * 4;
        float4 rd = *(const float4*)&rowp[sl];
        float vv[4] = {rd.x, rd.y, rd.z, rd.w};
#pragma unroll
        for (int e = 0; e < 4; ++e) {
          __bf16 h = (__bf16)vv[e];
          sBh[(sl + e) * 136 + pc] = h;
          sBl[(sl + e) * 136 + pc] = (__bf16)(vv[e] - (float)h);
        }
      }
  }
  __syncthreads();

  f32x4 zero = {0.f, 0.f, 0.f, 0.f};
  f32x4 acc[2][4];
#pragma unroll
  for (int mt = 0; mt < 2; ++mt)
#pragma unroll
    for (int nt = 0; nt < 4; ++nt) acc[mt][nt] = zero;

#pragma unroll
  for (int ks = 0; ks < 4; ++ks) {
    bf16x8 bh[4], bl[4];
#pragma unroll
    for (int nt = 0; nt < 4; ++nt) {
      int off = (nt * 16 + ln) * 136 + ks * 32 + q * 8;
      bh[nt] = *(const bf16x8*)&sBh[off];
      bl[nt] = *(const bf16x8*)&sBl[off];
    }
#pragma unroll
    for (int mt = 0; mt < 2; ++mt)
#pragma unroll
      for (int nt = 0; nt < 4; ++nt) {
        acc[mt][nt] = mfma16(ah[mt][ks], bh[nt], acc[mt][nt]);
        acc[mt][nt] = mfma16(ah[mt][ks], bl[nt], acc[mt][nt]);
        acc[mt][nt] = mfma16(al[mt][ks], bh[nt], acc[mt][nt]);
      }
  }

#pragma unroll
  for (int mt = 0; mt < 2; ++mt) {
    int rowb = w * 32 + mt * 16 + q * 4;
#pragma unroll
    for (int r = 0; r < 4; ++r) {
      float bv = bias[rowb + r];
      float vs[4];
      float sm = 0.f, sq = 0.f;
#pragma unroll
      for (int nt = 0; nt < 4; ++nt) {
        float v = acc[mt][nt][r] + bv;
        vs[nt] = v; sm += v; sq += v * v;
      }
#pragma unroll
      for (int off = 1; off < 16; off <<= 1) {
        sm += __shfl_xor(sm, off, 64);
        sq += __shfl_xor(sq, off, 64);
      }
      if (ln == 0) {
        atomicAdd(&part[bkt + (rowb + r) * 2 + 0], sm);
        atomicAdd(&part[bkt + (rowb + r) * 2 + 1], sq);
      }
#pragma unroll
      for (int nt = 0; nt < 4; ++nt)
        y[(size_t)((b << 7) + rowb + r) * SS + s0 + nt * 16 + ln] = vs[nt];
    }
  }
}

// ---------------- BN finalize (reduce buckets) ------------------------------
__global__ void bn_finalize(const float* __restrict__ buckets,
                            const float* __restrict__ g,
                            const float* __restrict__ beta, int goff,
                            float* __restrict__ scale, float* __restrict__ shift)
{
  int i = blockIdx.x * 256 + threadIdx.x;   // 0..383 = [role3][p][co]
  if (i >= 384) return;
  int role = i >> 7, pc = i & 127;
  float sm = 0.f, sq = 0.f;
  const float* bp = buckets + role * 256 + pc * 2;
#pragma unroll 4
  for (int k = 0; k < NBUCKET; ++k) {
    sm += bp[k * 768 + 0];
    sq += bp[k * 768 + 1];
  }
  const float inv = 1.f / 131072.f;
  float mu = sm * inv;
  float var = sq * inv - mu * mu;
  float istd = rsqrtf(var + 1e-5f);
  float gg = g[goff + role * 128 + pc];
  float bb = beta[goff + role * 128 + pc];
  float sc = gg * istd;
  scale[i] = sc;
  shift[i] = bb - mu * sc;
}

// ---------------- BN apply + leaky relu ------------------------------------
__global__ __launch_bounds__(256) void bn_apply(
    float* __restrict__ y, const float* __restrict__ scale,
    const float* __restrict__ shift)
{
  size_t i = (size_t)blockIdx.x * 256 + threadIdx.x;
  float4 v = ((float4*)y)[i];
  size_t fi = i << 2;
  int idx = (int)(fi >> 24) * 128 + (int)((fi >> 16) & 127);
  float sc = scale[idx], sh = shift[idx];
  float t;
  t = v.x * sc + sh; v.x = t > 0.f ? t : 0.01f * t;
  t = v.y * sc + sh; v.y = t > 0.f ? t : 0.01f * t;
  t = v.z * sc + sh; v.z = t > 0.f ? t : 0.01f * t;
  t = v.w * sc + sh; v.w = t > 0.f ? t : 0.01f * t;
  ((float4*)y)[i] = v;
}

// ============ complex scores (split-bf16 MFMA, split-K, atomics) ============
__global__ __launch_bounds__(256) void score_mfma(
    const float* __restrict__ qg, const float* __restrict__ kg,
    float* __restrict__ SR, float* __restrict__ SI, int freq)
{
  __shared__ __align__(16) __bf16 sQh[2 * 128 * 40], sQl[2 * 128 * 40];
  __shared__ __align__(16) __bf16 sKh[2 * 64 * 40],  sKl[2 * 64 * 40];
  const int tid = threadIdx.x;
  const int n0 = (blockIdx.x >> 2) * 128, m0 = (blockIdx.x & 3) * 64;
  const int d0 = blockIdx.y * 1024;
  const int b = blockIdx.z;
  const int w = tid >> 6, q4 = (tid >> 4) & 3, ln = tid & 15;
  const float* qp = qg + (size_t)b * 2 * PLANE;
  const float* kp = kg + (size_t)b * 2 * PLANE;

  f32x4 zero = {0.f, 0.f, 0.f, 0.f};
  f32x4 accr[2][4], acci[2][4];
#pragma unroll
  for (int st = 0; st < 2; ++st)
#pragma unroll
    for (int mt = 0; mt < 4; ++mt) { accr[st][mt] = zero; acci[st][mt] = zero; }

  for (int ch = 0; ch < 32; ++ch) {
    const int dd = d0 + ch * 32;
    if (!freq) {
#pragma unroll
      for (int r = 0; r < 8; ++r) {
        int u = tid + 256 * r;
        int tok4 = u & 31, dl = (u >> 5) & 31, p = u >> 10;
        float4 v4 = *(const float4*)&qp[(size_t)p * PLANE +
                                        (size_t)(dd + dl) * 256 + n0 + tok4 * 4];
        float vv[4] = {v4.x, v4.y, v4.z, v4.w};
#pragma unroll
        for (int e = 0; e < 4; ++e) {
          __bf16 h = (__bf16)vv[e];
          sQh[(p * 128 + tok4 * 4 + e) * 40 + dl] = h;
          sQl[(p * 128 + tok4 * 4 + e) * 40 + dl] = (__bf16)(vv[e] - (float)h);
        }
      }
#pragma unroll
      for (int r = 0; r < 4; ++r) {
        int u = tid + 256 * r;
        int tok4 = u & 15, dl = (u >> 4) & 31, p = u >> 9;
        float4 v4 = *(const float4*)&kp[(size_t)p * PLANE +
                                        (size_t)(dd + dl) * 256 + m0 + tok4 * 4];
        float vv[4] = {v4.x, v4.y, v4.z, v4.w};
#pragma unroll
        for (int e = 0; e < 4; ++e) {
          __bf16 h = (__bf16)vv[e];
          sKh[(p * 64 + tok4 * 4 + e) * 40 + dl] = h;
          sKl[(p * 64 + tok4 * 4 + e) * 40 + dl] = (__bf16)(vv[e] - (float)h);
        }
      }
    } else {
      const int c = dd >> 8, t0c = dd & 255;
#pragma unroll
      for (int r = 0; r < 8; ++r) {
        int u = tid + 256 * r;
        int dc = u & 7, tok = (u >> 3) & 127, p = u >> 10;
        float4 v4 = *(const float4*)&qp[(size_t)p * PLANE + (size_t)c * 65536 +
                                        t0c + dc * 4 + (size_t)(n0 + tok) * 256];
        float vv[4] = {v4.x, v4.y, v4.z, v4.w};
        bf16x4v hv, lv;
#pragma unroll
        for (int e = 0; e < 4; ++e) {
          __bf16 h = (__bf16)vv[e];
          hv[e] = h; lv[e] = (__bf16)(vv[e] - (float)h);
        }
        *(bf16x4v*)&sQh[(p * 128 + tok) * 40 + dc * 4] = hv;
        *(bf16x4v*)&sQl[(p * 128 + tok) * 40 + dc * 4] = lv;
      }
#pragma unroll
      for (int r = 0; r < 4; ++r) {
        int u = tid + 256 * r;
        int dc = u & 7, tok = (u >> 3) & 63, p = u >> 9;
        float4 v4 = *(const float4*)&kp[(size_t)p * PLANE + (size_t)c * 65536 +
                                        t0c + dc * 4 + (size_t)(m0 + tok) * 256];
        float vv[4] = {v4.x, v4.y, v4.z, v4.w};
        bf16x4v hv, lv;
#pragma unroll
        for (int e = 0; e < 4; ++e) {
          __bf16 h = (__bf16)vv[e];
          hv[e] = h; lv[e] = (__bf16)(vv[e] - (float)h);
        }
        *(bf16x4v*)&sKh[(p * 64 + tok) * 40 + dc * 4] = hv;
        *(bf16x4v*)&sKl[(p * 64 + tok) * 40 + dc * 4] = lv;
      }
    }
    __syncthreads();

    bf16x8 qh[2][2], ql2[2][2], nqh[2], nql[2];
#pragma unroll
    for (int st = 0; st < 2; ++st) {
      int tokn = w * 32 + st * 16 + ln;
#pragma unroll
      for (int p = 0; p < 2; ++p) {
        qh[st][p]  = *(const bf16x8*)&sQh[(p * 128 + tokn) * 40 + q4 * 8];
        ql2[st][p] = *(const bf16x8*)&sQl[(p * 128 + tokn) * 40 + q4 * 8];
      }
      nqh[st] = neg8(qh[st][0]);
      nql[st] = neg8(ql2[st][0]);
    }
#pragma unroll
    for (int mt = 0; mt < 4; ++mt) {
      int tk = mt * 16 + ln;
      bf16x8 krh = *(const bf16x8*)&sKh[tk * 40 + q4 * 8];
      bf16x8 krl = *(const bf16x8*)&sKl[tk * 40 + q4 * 8];
      bf16x8 kih = *(const bf16x8*)&sKh[(64 + tk) * 40 + q4 * 8];
      bf16x8 kil = *(const bf16x8*)&sKl[(64 + tk) * 40 + q4 * 8];
#pragma unroll
      for (int st = 0; st < 2; ++st) {
        f32x4 ar = accr[st][mt], ai = acci[st][mt];
        ar = mfma16(qh[st][0], krh, ar);
        ar = mfma16(qh[st][0], krl, ar);
        ar = mfma16(ql2[st][0], krh, ar);
        ar = mfma16(qh[st][1], kih, ar);
        ar = mfma16(qh[st][1], kil, ar);
        ar = mfma16(ql2[st][1], kih, ar);
        ai = mfma16(qh[st][1], krh, ai);
        ai = mfma16(qh[st][1], krl, ai);
        ai = mfma16(ql2[st][1], krh, ai);
        ai = mfma16(nqh[st], kih, ai);
        ai = mfma16(nqh[st], kil, ai);
        ai = mfma16(nql[st], kih, ai);
        accr[st][mt] = ar; acci[st][mt] = ai;
      }
    }
    __syncthreads();
  }

#pragma unroll
  for (int st = 0; st < 2; ++st)
#pragma unroll
    for (int mt = 0; mt < 4; ++mt)
#pragma unroll
      for (int r = 0; r < 4; ++r) {
        int n = n0 + w * 32 + st * 16 + q4 * 4 + r;
        int m = m0 + mt * 16 + ln;
        int idx = (b << 16) + (n << 8) + m;
        atomicAdd(&SR[idx], accr[st][mt][r]);
        atomicAdd(&SI[idx], acci[st][mt][r]);
      }
}

// ---------------- softmax over n (axis=1), per (b,m) column -----------------
__global__ __launch_bounds__(256) void softmax_kernel(
    const float* __restrict__ sr, const float* __restrict__ si,
    float* __restrict__ am)
{
  const int m = blockIdx.x & 255;
  const int b = blockIdx.x >> 8;
  const int n = threadIdx.x;
  const int idx = (b << 16) + (n << 8) + m;
  float vr = sr[idx], vi = si[idx];
  float mag = sqrtf(vr * vr + vi * vi);
  __shared__ float wmax[4];
  __shared__ float wsum[4];
  float mx = mag;
  #pragma unroll
  for (int off = 1; off < 64; off <<= 1)
    mx = fmaxf(mx, __shfl_xor(mx, off, 64));
  if ((threadIdx.x & 63) == 0) wmax[threadIdx.x >> 6] = mx;
  __syncthreads();
  mx = fmaxf(fmaxf(wmax[0], wmax[1]), fmaxf(wmax[2], wmax[3]));
  float e = expf(mag - mx);
  float sm = e;
  #pragma unroll
  for (int off = 1; off < 64; off <<= 1)
    sm += __shfl_xor(sm, off, 64);
  if ((threadIdx.x & 63) == 0) wsum[threadIdx.x >> 6] = sm;
  __syncthreads();
  float tot = wsum[0] + wsum[1] + wsum[2] + wsum[3];
  am[idx] = e / tot;
}

// ======== V prep: post-BN V -> bf16 hi/lo, uniform [d][m] layout ============
// time phase: [d][m] already linear -> straight convert
__global__ __launch_bounds__(256) void vt_convert(
    const float* __restrict__ y2, __bf16* __restrict__ vh, __bf16* __restrict__ vl)
{
  size_t i = ((size_t)blockIdx.x * 256 + threadIdx.x) << 2;
  float4 v = *(const float4*)&y2[i];
  float vv[4] = {v.x, v.y, v.z, v.w};
  bf16x4v h, l;
#pragma unroll
  for (int e = 0; e < 4; ++e) {
    __bf16 hh = (__bf16)vv[e];
    h[e] = hh; l[e] = (__bf16)(vv[e] - (float)hh);
  }
  *(bf16x4v*)&vh[i] = h;
  *(bf16x4v*)&vl[i] = l;
}

// freq phase: V[d=c*256+t][m=f] = Y2[c][f*256+t] -> 64x64 LDS tile transpose
__global__ __launch_bounds__(256) void vt_transpose(
    const float* __restrict__ y2, __bf16* __restrict__ vh, __bf16* __restrict__ vl)
{
  __shared__ float sT[64 * 65];
  const int tid = threadIdx.x;
  const int bpc = blockIdx.y;           // bp*64 + c
  const int bp = bpc >> 6, c = bpc & 63;
  const int f0 = (blockIdx.x >> 2) << 6, t0 = (blockIdx.x & 3) << 6;
  const float* src = y2 + (size_t)bp * PLANE + (size_t)c * SS;
#pragma unroll
  for (int r = 0; r < 4; ++r) {
    int fl = (tid >> 4) + (r << 4);
    int tl = (tid & 15) << 2;
    float4 v = *(const float4*)&src[(f0 + fl) * 256 + t0 + tl];
    sT[fl * 65 + tl + 0] = v.x;
    sT[fl * 65 + tl + 1] = v.y;
    sT[fl * 65 + tl + 2] = v.z;
    sT[fl * 65 + tl + 3] = v.w;
  }
  __syncthreads();
  __bf16* dsth = vh + (((size_t)bp * 16384 + c * 256) << 8);
  __bf16* dstl = vl + (((size_t)bp * 16384 + c * 256) << 8);
#pragma unroll
  for (int r = 0; r < 4; ++r) {
    int tl = (tid >> 4) + (r << 4);
    int fl = (tid & 15) << 2;
    bf16x4v h, l;
#pragma unroll
    for (int e = 0; e < 4; ++e) {
      float vv = sT[(fl + e) * 65 + tl];
      __bf16 hh = (__bf16)vv;
      h[e] = hh; l[e] = (__bf16)(vv - (float)hh);
    }
    *(bf16x4v*)&dsth[(size_t)(t0 + tl) * 256 + f0 + fl] = h;
    *(bf16x4v*)&dstl[(size_t)(t0 + tl) * 256 + f0 + fl] = l;
  }
}

// ======== out[d,n] = sum_m A[n,m] * V[d,m] via split-bf16 MFMA ==============
// tile: 128 d x 64 n, BK=64, 4 waves (wave = 32 d rows x 64 n), cconv geometry
__global__ __launch_bounds__(256) void av_mfma(
    const float* __restrict__ am, const __bf16* __restrict__ vth,
    const __bf16* __restrict__ vtl, float* __restrict__ out, int freq)
{
  __shared__ __align__(16) char smem[55296];
  __bf16* sVh = (__bf16*)smem;                  // [128][72]
  __bf16* sVl = (__bf16*)(smem + 18432);
  __bf16* sAh = (__bf16*)(smem + 36864);        // [64][72]
  __bf16* sAl = (__bf16*)(smem + 46080);
  const int tid = threadIdx.x;
  const int d0 = blockIdx.x << 7;
  const int n0 = blockIdx.y << 6;
  const int bp = blockIdx.z, b = bp >> 1;
  const int w = tid >> 6, q = (tid >> 4) & 3, ln = tid & 15;
  const __bf16* vhp = vth + (((size_t)bp * 16384 + d0) << 8);
  const __bf16* vlp = vtl + (((size_t)bp * 16384 + d0) << 8);
  float* op = out + (size_t)bp * PLANE;

  f32x4 zero = {0.f, 0.f, 0.f, 0.f};
  f32x4 acc[2][4];
#pragma unroll
  for (int mt = 0; mt < 2; ++mt)
#pragma unroll
    for (int nt = 0; nt < 4; ++nt) acc[mt][nt] = zero;

  for (int m0 = 0; m0 < 256; m0 += 64) {
    // stage V tile [128][64] hi/lo (bf16, straight copy, b128 in/out)
#pragma unroll
    for (int r = 0; r < 4; ++r) {
      int u = tid + (r << 8);
      int dl = u >> 3, g = (u & 7) << 3;
      *(bf16x8*)&sVh[dl * 72 + g] = *(const bf16x8*)&vhp[dl * 256 + m0 + g];
      *(bf16x8*)&sVl[dl * 72 + g] = *(const bf16x8*)&vlp[dl * 256 + m0 + g];
    }
    // stage A tile [64][64] fp32 -> split hi/lo
#pragma unroll
    for (int r = 0; r < 4; ++r) {
      int u = tid + (r << 8);
      int mj = (u & 15) << 2, nl = u >> 4;
      float4 v4 = *(const float4*)&am[(b << 16) + ((n0 + nl) << 8) + m0 + mj];
      float vv[4] = {v4.x, v4.y, v4.z, v4.w};
      bf16x4v h, l;
#pragma unroll
      for (int e = 0; e < 4; ++e) {
        __bf16 hh = (__bf16)vv[e];
        h[e] = hh; l[e] = (__bf16)(vv[e] - (float)hh);
      }
      *(bf16x4v*)&sAh[nl * 72 + mj] = h;
      *(bf16x4v*)&sAl[nl * 72 + mj] = l;
    }
    __syncthreads();

#pragma unroll
    for (int ks = 0; ks < 2; ++ks) {
      bf16x8 vhf[2], vlf[2], ahf[4], alf[4];
#pragma unroll
      for (int mt = 0; mt < 2; ++mt) {
        int off = (w * 32 + mt * 16 + ln) * 72 + ks * 32 + q * 8;
        vhf[mt] = *(const bf16x8*)&sVh[off];
        vlf[mt] = *(const bf16x8*)&sVl[off];
      }
#pragma unroll
      for (int nt = 0; nt < 4; ++nt) {
        int off = (nt * 16 + ln) * 72 + ks * 32 + q * 8;
        ahf[nt] = *(const bf16x8*)&sAh[off];
        alf[nt] = *(const bf16x8*)&sAl[off];
      }
#pragma unroll
      for (int mt = 0; mt < 2; ++mt)
#pragma unroll
        for (int nt = 0; nt < 4; ++nt) {
          f32x4 a = acc[mt][nt];
          a = mfma16(vhf[mt], ahf[nt], a);
          a = mfma16(vhf[mt], alf[nt], a);
          a = mfma16(vlf[mt], ahf[nt], a);
          acc[mt][nt] = a;
        }
    }
    __syncthreads();
  }

  if (!freq) {
    // time phase: direct [d][n] store (phase 0, no accumulate)
#pragma unroll
    for (int mt = 0; mt < 2; ++mt)
#pragma unroll
      for (int nt = 0; nt < 4; ++nt)
#pragma unroll
        for (int r = 0; r < 4; ++r) {
          int row = d0 + w * 32 + mt * 16 + q * 4 + r;
          op[(size_t)row * 256 + n0 + nt * 16 + ln] = acc[mt][nt][r];
        }
  } else {
    // freq phase: LDS transpose so global RMW stays float4 along t
    float* sO = (float*)smem;   // [128][65] = 33280 B (fits in smem)
#pragma unroll
    for (int mt = 0; mt < 2; ++mt)
#pragma unroll
      for (int nt = 0; nt < 4; ++nt)
#pragma unroll
        for (int r = 0; r < 4; ++r)
          sO[(w * 32 + mt * 16 + q * 4 + r) * 65 + nt * 16 + ln] = acc[mt][nt][r];
    __syncthreads();
    const int c = d0 >> 8, t0 = d0 & 255;
    const int dl = (tid & 31) << 2, nb = tid >> 5;
#pragma unroll
    for (int r = 0; r < 8; ++r) {
      int n = nb + (r << 3);
      float4 wv = make_float4(sO[(dl + 0) * 65 + n], sO[(dl + 1) * 65 + n],
                              sO[(dl + 2) * 65 + n], sO[(dl + 3) * 65 + n]);
      size_t addr = (size_t)c * SS + (size_t)(n0 + n) * 256 + t0 + dl;
      float4 o = *(float4*)&op[addr];
      wv.x += o.x; wv.y += o.y; wv.z += o.z; wv.w += o.w;
      *(float4*)&op[addr] = wv;
    }
  }
}

extern "C" void kernel_launch(void* const* d_in, const int* in_sizes, int n_in,
                              void* d_out, int out_size, void* d_ws, size_t ws_size,
                              hipStream_t stream) {
  const float* P    = (const float*)d_in[0];
  const float* Q    = (const float*)d_in[1];
  const float* W    = (const float*)d_in[2];
  const float* bias = (const float*)d_in[3];
  const float* g    = (const float*)d_in[4];
  const float* beta = (const float*)d_in[5];
  float* out = (float*)d_out;
  float* ws  = (float*)d_ws;

  float* Y0    = ws;
  float* Y1    = Y0 + TEN_ELEMS;
  float* Y2    = Y1 + TEN_ELEMS;
  float* SR    = Y2 + TEN_ELEMS;
  float* SI    = SR + 131072;
  float* AM    = SI + 131072;
  float* BUCK  = AM + 131072;             // 64 * 768 = 49152 floats
  float* SCALE = BUCK + NBUCKET * 768;    // 384
  float* SHIFT = SCALE + 384;             // 384

  // V bf16 hi/lo live in Y0's slot (Y0 is dead after score_mfma):
  // 16777216 bf16 each = 32 MiB + 32 MiB, fits in Y0's 64 MiB exactly.
  __bf16* VTh = (__bf16*)Y0;
  __bf16* VTl = VTh + TEN_ELEMS;

  for (int phase = 0; phase < 2; ++phase) {
    int j0 = phase * 3;
    int freq = phase;
    hipMemsetAsync(BUCK, 0, NBUCKET * 768 * sizeof(float), stream);
    cconv_mfma<<<dim3(1024, 2), 256, 0, stream>>>(
        Q, W + (size_t)j0 * 8192, bias + j0 * 128, Y0, BUCK);
    cconv_mfma<<<dim3(1024, 2), 256, 0, stream>>>(
        P, W + (size_t)(j0 + 1) * 8192, bias + (j0 + 1) * 128, Y1, BUCK + 256);
    cconv_mfma<<<dim3(1024, 2), 256, 0, stream>>>(
        P, W + (size_t)(j0 + 2) * 8192, bias + (j0 + 2) * 128, Y2, BUCK + 512);
    bn_finalize<<<2, 256, 0, stream>>>(BUCK, g, beta, j0 * 128, SCALE, SHIFT);
    bn_apply<<<49152, 256, 0, stream>>>(Y0, SCALE, SHIFT);   // covers Y0..Y2
    hipMemsetAsync(SR, 0, 2 * 131072 * sizeof(float), stream);
    score_mfma<<<dim3(8, 16, 2), 256, 0, stream>>>(Y0, Y1, SR, SI, freq);
    softmax_kernel<<<512, 256, 0, stream>>>(SR, SI, AM);
    if (!freq)
      vt_convert<<<16384, 256, 0, stream>>>(Y2, VTh, VTl);
    else
      vt_transpose<<<dim3(16, 256), 256, 0, stream>>>(Y2, VTh, VTl);
    av_mfma<<<dim3(128, 4, 4), 256, 0, stream>>>(AM, VTh, VTl, out, freq);
  }
}

// Round 2
// 864.708 us; speedup vs baseline: 1.1433x; 1.1433x over previous
//
#include <hip/hip_runtime.h>
#include <math.h>

#define SS 65536               // F*T
#define PLANE 4194304          // CC*SS floats per (b,part)
#define TEN_ELEMS 16777216     // 2*2*CC*SS floats per tensor
#define NBUCKET 64

typedef __bf16 bf16x8 __attribute__((ext_vector_type(8)));
typedef __bf16 bf16x4v __attribute__((ext_vector_type(4)));
typedef float  f32x4  __attribute__((ext_vector_type(4)));

__device__ inline f32x4 mfma16(bf16x8 a, bf16x8 b, f32x4 c) {
  return __builtin_amdgcn_mfma_f32_16x16x32_bf16(a, b, c, 0, 0, 0);
}
__device__ inline bf16x8 neg8(bf16x8 v) {
  union { bf16x8 b; unsigned u[4]; } t; t.b = v;
#pragma unroll
  for (int i = 0; i < 4; ++i) t.u[i] ^= 0x80008000u;
  return t.b;
}

// swizzled element offset of 16B-granule g within row r (rows of 40 elems):
// key = ((r>>2)^(r>>4))&3 is lane-varying for every staging pattern; the
// p-part offsets (128 for Q rows, 64 for K rows) contribute 0 mod 4 to both
// r>>2 and r>>4, so one formula serves Q and K, stores and reads.
__device__ inline int swz(int r, int g) {
  return r * 40 + (((g ^ (r >> 2) ^ (r >> 4)) & 3) << 3);
}

// ============ complex 1x1 conv (split-bf16 MFMA) + bias + BN stats ==========
__global__ __launch_bounds__(256) void cconv_mfma(
    const float* __restrict__ x, const float* __restrict__ Wj,
    const float* __restrict__ bias, float* __restrict__ y,
    float* __restrict__ part)
{
  __shared__ __align__(16) __bf16 sBh[64 * 136];   // [s][pc] hi
  __shared__ __align__(16) __bf16 sBl[64 * 136];   // [s][pc] lo
  const int tid = threadIdx.x;
  const int b = blockIdx.y;
  const int s0 = blockIdx.x << 6;
  const int bkt = (blockIdx.x & (NBUCKET - 1)) * 768;
  const int w = tid >> 6, q = (tid >> 4) & 3, ln = tid & 15;

  bf16x8 ah[2][4], al[2][4];
#pragma unroll
  for (int mt = 0; mt < 2; ++mt) {
    int row = w * 32 + mt * 16 + ln;
    int po = row >> 6, co = row & 63;
#pragma unroll
    for (int ks = 0; ks < 4; ++ks) {
      bf16x8 vh, vl;
#pragma unroll
      for (int j = 0; j < 8; ++j) {
        int k = ks * 32 + q * 8 + j;
        int pi = k >> 6, c = k & 63;
        float v = Wj[((po ^ pi) << 12) + co * 64 + c];
        if (po == 0 && pi == 1) v = -v;
        __bf16 h = (__bf16)v;
        vh[j] = h;
        vl[j] = (__bf16)(v - (float)h);
      }
      ah[mt][ks] = vh; al[mt][ks] = vl;
    }
  }

#pragma unroll
  for (int ph = 0; ph < 2; ++ph) {
    int pc = ph * 64 + (tid & 63);
    const float* rowp = x + (size_t)(b * 128 + pc) * SS + s0;
#pragma unroll
    for (int sh2 = 0; sh2 < 2; ++sh2)
#pragma unroll
      for (int sc2 = 0; sc2 < 2; ++sc2) {
        int sl = ((tid >> 6) << 3) + sh2 * 32 + sc2 * 4;
        float4 rd = *(const float4*)&rowp[sl];
        float vv[4] = {rd.x, rd.y, rd.z, rd.w};
#pragma unroll
        for (int e = 0; e < 4; ++e) {
          __bf16 h = (__bf16)vv[e];
          sBh[(sl + e) * 136 + pc] = h;
          sBl[(sl + e) * 136 + pc] = (__bf16)(vv[e] - (float)h);
        }
      }
  }
  __syncthreads();

  f32x4 zero = {0.f, 0.f, 0.f, 0.f};
  f32x4 acc[2][4];
#pragma unroll
  for (int mt = 0; mt < 2; ++mt)
#pragma unroll
    for (int nt = 0; nt < 4; ++nt) acc[mt][nt] = zero;

#pragma unroll
  for (int ks = 0; ks < 4; ++ks) {
    bf16x8 bh[4], bl[4];
#pragma unroll
    for (int nt = 0; nt < 4; ++nt) {
      int off = (nt * 16 + ln) * 136 + ks * 32 + q * 8;
      bh[nt] = *(const bf16x8*)&sBh[off];
      bl[nt] = *(const bf16x8*)&sBl[off];
    }
#pragma unroll
    for (int mt = 0; mt < 2; ++mt)
#pragma unroll
      for (int nt = 0; nt < 4; ++nt) {
        acc[mt][nt] = mfma16(ah[mt][ks], bh[nt], acc[mt][nt]);
        acc[mt][nt] = mfma16(ah[mt][ks], bl[nt], acc[mt][nt]);
        acc[mt][nt] = mfma16(al[mt][ks], bh[nt], acc[mt][nt]);
      }
  }

#pragma unroll
  for (int mt = 0; mt < 2; ++mt) {
    int rowb = w * 32 + mt * 16 + q * 4;
#pragma unroll
    for (int r = 0; r < 4; ++r) {
      float bv = bias[rowb + r];
      float vs[4];
      float sm = 0.f, sq = 0.f;
#pragma unroll
      for (int nt = 0; nt < 4; ++nt) {
        float v = acc[mt][nt][r] + bv;
        vs[nt] = v; sm += v; sq += v * v;
      }
#pragma unroll
      for (int off = 1; off < 16; off <<= 1) {
        sm += __shfl_xor(sm, off, 64);
        sq += __shfl_xor(sq, off, 64);
      }
      if (ln == 0) {
        atomicAdd(&part[bkt + (rowb + r) * 2 + 0], sm);
        atomicAdd(&part[bkt + (rowb + r) * 2 + 1], sq);
      }
#pragma unroll
      for (int nt = 0; nt < 4; ++nt)
        y[(size_t)((b << 7) + rowb + r) * SS + s0 + nt * 16 + ln] = vs[nt];
    }
  }
}

// ---------------- BN finalize (reduce buckets) ------------------------------
__global__ void bn_finalize(const float* __restrict__ buckets,
                            const float* __restrict__ g,
                            const float* __restrict__ beta, int goff,
                            float* __restrict__ scale, float* __restrict__ shift)
{
  int i = blockIdx.x * 256 + threadIdx.x;   // 0..383 = [role3][p][co]
  if (i >= 384) return;
  int role = i >> 7, pc = i & 127;
  float sm = 0.f, sq = 0.f;
  const float* bp = buckets + role * 256 + pc * 2;
#pragma unroll 4
  for (int k = 0; k < NBUCKET; ++k) {
    sm += bp[k * 768 + 0];
    sq += bp[k * 768 + 1];
  }
  const float inv = 1.f / 131072.f;
  float mu = sm * inv;
  float var = sq * inv - mu * mu;
  float istd = rsqrtf(var + 1e-5f);
  float gg = g[goff + role * 128 + pc];
  float bb = beta[goff + role * 128 + pc];
  float sc = gg * istd;
  scale[i] = sc;
  shift[i] = bb - mu * sc;
}

// ---------------- BN apply + leaky relu ------------------------------------
__global__ __launch_bounds__(256) void bn_apply(
    float* __restrict__ y, const float* __restrict__ scale,
    const float* __restrict__ shift)
{
  size_t i = (size_t)blockIdx.x * 256 + threadIdx.x;
  float4 v = ((float4*)y)[i];
  size_t fi = i << 2;
  int idx = (int)(fi >> 24) * 128 + (int)((fi >> 16) & 127);
  float sc = scale[idx], sh = shift[idx];
  float t;
  t = v.x * sc + sh; v.x = t > 0.f ? t : 0.01f * t;
  t = v.y * sc + sh; v.y = t > 0.f ? t : 0.01f * t;
  t = v.z * sc + sh; v.z = t > 0.f ? t : 0.01f * t;
  t = v.w * sc + sh; v.w = t > 0.f ? t : 0.01f * t;
  ((float4*)y)[i] = v;
}

// ============ complex scores (split-bf16 MFMA, split-K, atomics) ============
// grid dim3(8,32,2) = 512 blocks. Role remap so the 4 m0-blocks sharing the
// same (b,n0,d0) Q-slice land on one XCD (bid%8 round-robin assumption):
//   sid&7  -> (n0, b, d-half)   sid>>3 -> (m0, d-sub)
__global__ __launch_bounds__(256) void score_mfma(
    const float* __restrict__ qg, const float* __restrict__ kg,
    float* __restrict__ SR, float* __restrict__ SI, int freq)
{
  __shared__ __align__(16) __bf16 sQh[2 * 128 * 40], sQl[2 * 128 * 40];
  __shared__ __align__(16) __bf16 sKh[2 * 64 * 40],  sKl[2 * 64 * 40];
  const int tid = threadIdx.x;
  const int sid = blockIdx.x + (blockIdx.y << 3) + (blockIdx.z << 8);
  const int kk = sid & 7, tt = sid >> 3;
  const int n0 = (kk & 1) << 7;
  const int b  = (kk >> 1) & 1;
  const int m0 = (tt & 3) << 6;
  const int d0 = (((kk >> 2) << 4) + (tt >> 2)) << 9;   // 32 splits x 512
  const int w = tid >> 6, q4 = (tid >> 4) & 3, ln = tid & 15;
  const float* qp = qg + (size_t)b * 2 * PLANE;
  const float* kp = kg + (size_t)b * 2 * PLANE;

  f32x4 zero = {0.f, 0.f, 0.f, 0.f};
  f32x4 accr[2][4], acci[2][4];
#pragma unroll
  for (int st = 0; st < 2; ++st)
#pragma unroll
    for (int mt = 0; mt < 4; ++mt) { accr[st][mt] = zero; acci[st][mt] = zero; }

  for (int ch = 0; ch < 16; ++ch) {
    const int dd = d0 + ch * 32;
    if (!freq) {
#pragma unroll
      for (int r = 0; r < 8; ++r) {
        int u = tid + 256 * r;
        int tok4 = u & 31, dl = (u >> 5) & 31, p = u >> 10;
        float4 v4 = *(const float4*)&qp[(size_t)p * PLANE +
                                        (size_t)(dd + dl) * 256 + n0 + tok4 * 4];
        float vv[4] = {v4.x, v4.y, v4.z, v4.w};
#pragma unroll
        for (int e = 0; e < 4; ++e) {
          int row = p * 128 + tok4 * 4 + e;
          int off = swz(row, dl >> 3) + (dl & 7);
          __bf16 h = (__bf16)vv[e];
          sQh[off] = h;
          sQl[off] = (__bf16)(vv[e] - (float)h);
        }
      }
#pragma unroll
      for (int r = 0; r < 4; ++r) {
        int u = tid + 256 * r;
        int tok4 = u & 15, dl = (u >> 4) & 31, p = u >> 9;
        float4 v4 = *(const float4*)&kp[(size_t)p * PLANE +
                                        (size_t)(dd + dl) * 256 + m0 + tok4 * 4];
        float vv[4] = {v4.x, v4.y, v4.z, v4.w};
#pragma unroll
        for (int e = 0; e < 4; ++e) {
          int row = p * 64 + tok4 * 4 + e;
          int off = swz(row, dl >> 3) + (dl & 7);
          __bf16 h = (__bf16)vv[e];
          sKh[off] = h;
          sKl[off] = (__bf16)(vv[e] - (float)h);
        }
      }
    } else {
      const int c = dd >> 8, t0c = dd & 255;
#pragma unroll
      for (int r = 0; r < 8; ++r) {
        int u = tid + 256 * r;
        int dc = u & 7, tok = (u >> 3) & 127, p = u >> 10;
        float4 v4 = *(const float4*)&qp[(size_t)p * PLANE + (size_t)c * 65536 +
                                        t0c + dc * 4 + (size_t)(n0 + tok) * 256];
        float vv[4] = {v4.x, v4.y, v4.z, v4.w};
        bf16x4v hv, lv;
#pragma unroll
        for (int e = 0; e < 4; ++e) {
          __bf16 h = (__bf16)vv[e];
          hv[e] = h; lv[e] = (__bf16)(vv[e] - (float)h);
        }
        int row = p * 128 + tok;
        int off = swz(row, dc >> 1) + ((dc & 1) << 2);
        *(bf16x4v*)&sQh[off] = hv;
        *(bf16x4v*)&sQl[off] = lv;
      }
#pragma unroll
      for (int r = 0; r < 4; ++r) {
        int u = tid + 256 * r;
        int dc = u & 7, tok = (u >> 3) & 63, p = u >> 9;
        float4 v4 = *(const float4*)&kp[(size_t)p * PLANE + (size_t)c * 65536 +
                                        t0c + dc * 4 + (size_t)(m0 + tok) * 256];
        float vv[4] = {v4.x, v4.y, v4.z, v4.w};
        bf16x4v hv, lv;
#pragma unroll
        for (int e = 0; e < 4; ++e) {
          __bf16 h = (__bf16)vv[e];
          hv[e] = h; lv[e] = (__bf16)(vv[e] - (float)h);
        }
        int row = p * 64 + tok;
        int off = swz(row, dc >> 1) + ((dc & 1) << 2);
        *(bf16x4v*)&sKh[off] = hv;
        *(bf16x4v*)&sKl[off] = lv;
      }
    }
    __syncthreads();

    bf16x8 qh[2][2], ql2[2][2], nqh[2], nql[2];
#pragma unroll
    for (int st = 0; st < 2; ++st) {
      int tokn = w * 32 + st * 16 + ln;
#pragma unroll
      for (int p = 0; p < 2; ++p) {
        int off = swz(p * 128 + tokn, q4);
        qh[st][p]  = *(const bf16x8*)&sQh[off];
        ql2[st][p] = *(const bf16x8*)&sQl[off];
      }
      nqh[st] = neg8(qh[st][0]);
      nql[st] = neg8(ql2[st][0]);
    }
#pragma unroll
    for (int mt = 0; mt < 4; ++mt) {
      int tk = mt * 16 + ln;
      int offr = swz(tk, q4), offi = swz(64 + tk, q4);
      bf16x8 krh = *(const bf16x8*)&sKh[offr];
      bf16x8 krl = *(const bf16x8*)&sKl[offr];
      bf16x8 kih = *(const bf16x8*)&sKh[offi];
      bf16x8 kil = *(const bf16x8*)&sKl[offi];
#pragma unroll
      for (int st = 0; st < 2; ++st) {
        f32x4 ar = accr[st][mt], ai = acci[st][mt];
        ar = mfma16(qh[st][0], krh, ar);
        ar = mfma16(qh[st][0], krl, ar);
        ar = mfma16(ql2[st][0], krh, ar);
        ar = mfma16(qh[st][1], kih, ar);
        ar = mfma16(qh[st][1], kil, ar);
        ar = mfma16(ql2[st][1], kih, ar);
        ai = mfma16(qh[st][1], krh, ai);
        ai = mfma16(qh[st][1], krl, ai);
        ai = mfma16(ql2[st][1], krh, ai);
        ai = mfma16(nqh[st], kih, ai);
        ai = mfma16(nqh[st], kil, ai);
        ai = mfma16(nql[st], kih, ai);
        accr[st][mt] = ar; acci[st][mt] = ai;
      }
    }
    __syncthreads();
  }

#pragma unroll
  for (int st = 0; st < 2; ++st)
#pragma unroll
    for (int mt = 0; mt < 4; ++mt)
#pragma unroll
      for (int r = 0; r < 4; ++r) {
        int n = n0 + w * 32 + st * 16 + q4 * 4 + r;
        int m = m0 + mt * 16 + ln;
        int idx = (b << 16) + (n << 8) + m;
        atomicAdd(&SR[idx], accr[st][mt][r]);
        atomicAdd(&SI[idx], acci[st][mt][r]);
      }
}

// ---------------- softmax over n (axis=1), per (b,m) column -----------------
__global__ __launch_bounds__(256) void softmax_kernel(
    const float* __restrict__ sr, const float* __restrict__ si,
    float* __restrict__ am)
{
  const int m = blockIdx.x & 255;
  const int b = blockIdx.x >> 8;
  const int n = threadIdx.x;
  const int idx = (b << 16) + (n << 8) + m;
  float vr = sr[idx], vi = si[idx];
  float mag = sqrtf(vr * vr + vi * vi);
  __shared__ float wmax[4];
  __shared__ float wsum[4];
  float mx = mag;
  #pragma unroll
  for (int off = 1; off < 64; off <<= 1)
    mx = fmaxf(mx, __shfl_xor(mx, off, 64));
  if ((threadIdx.x & 63) == 0) wmax[threadIdx.x >> 6] = mx;
  __syncthreads();
  mx = fmaxf(fmaxf(wmax[0], wmax[1]), fmaxf(wmax[2], wmax[3]));
  float e = expf(mag - mx);
  float sm = e;
  #pragma unroll
  for (int off = 1; off < 64; off <<= 1)
    sm += __shfl_xor(sm, off, 64);
  if ((threadIdx.x & 63) == 0) wsum[threadIdx.x >> 6] = sm;
  __syncthreads();
  float tot = wsum[0] + wsum[1] + wsum[2] + wsum[3];
  am[idx] = e / tot;
}

// ======== V prep: post-BN V -> bf16 hi/lo, uniform [d][m] layout ============
// time phase: [d][m] already linear -> straight convert
__global__ __launch_bounds__(256) void vt_convert(
    const float* __restrict__ y2, __bf16* __restrict__ vh, __bf16* __restrict__ vl)
{
  size_t i = ((size_t)blockIdx.x * 256 + threadIdx.x) << 2;
  float4 v = *(const float4*)&y2[i];
  float vv[4] = {v.x, v.y, v.z, v.w};
  bf16x4v h, l;
#pragma unroll
  for (int e = 0; e < 4; ++e) {
    __bf16 hh = (__bf16)vv[e];
    h[e] = hh; l[e] = (__bf16)(vv[e] - (float)hh);
  }
  *(bf16x4v*)&vh[i] = h;
  *(bf16x4v*)&vl[i] = l;
}

// freq phase: V[d=c*256+t][m=f] = Y2[c][f*256+t] -> 64x64 LDS tile transpose
__global__ __launch_bounds__(256) void vt_transpose(
    const float* __restrict__ y2, __bf16* __restrict__ vh, __bf16* __restrict__ vl)
{
  __shared__ float sT[64 * 65];
  const int tid = threadIdx.x;
  const int bpc = blockIdx.y;           // bp*64 + c
  const int bp = bpc >> 6, c = bpc & 63;
  const int f0 = (blockIdx.x >> 2) << 6, t0 = (blockIdx.x & 3) << 6;
  const float* src = y2 + (size_t)bp * PLANE + (size_t)c * SS;
#pragma unroll
  for (int r = 0; r < 4; ++r) {
    int fl = (tid >> 4) + (r << 4);
    int tl = (tid & 15) << 2;
    float4 v = *(const float4*)&src[(f0 + fl) * 256 + t0 + tl];
    sT[fl * 65 + tl + 0] = v.x;
    sT[fl * 65 + tl + 1] = v.y;
    sT[fl * 65 + tl + 2] = v.z;
    sT[fl * 65 + tl + 3] = v.w;
  }
  __syncthreads();
  __bf16* dsth = vh + (((size_t)bp * 16384 + c * 256) << 8);
  __bf16* dstl = vl + (((size_t)bp * 16384 + c * 256) << 8);
#pragma unroll
  for (int r = 0; r < 4; ++r) {
    int tl = (tid >> 4) + (r << 4);
    int fl = (tid & 15) << 2;
    bf16x4v h, l;
#pragma unroll
    for (int e = 0; e < 4; ++e) {
      float vv = sT[(fl + e) * 65 + tl];
      __bf16 hh = (__bf16)vv;
      h[e] = hh; l[e] = (__bf16)(vv - (float)hh);
    }
    *(bf16x4v*)&dsth[(size_t)(t0 + tl) * 256 + f0 + fl] = h;
    *(bf16x4v*)&dstl[(size_t)(t0 + tl) * 256 + f0 + fl] = l;
  }
}

// ======== out[d,n] = sum_m A[n,m] * V[d,m] via split-bf16 MFMA ==============
// tile: 128 d x 64 n, BK=64, 4 waves (wave = 32 d rows x 64 n), cconv geometry
__global__ __launch_bounds__(256) void av_mfma(
    const float* __restrict__ am, const __bf16* __restrict__ vth,
    const __bf16* __restrict__ vtl, float* __restrict__ out, int freq)
{
  __shared__ __align__(16) char smem[55296];
  __bf16* sVh = (__bf16*)smem;                  // [128][72]
  __bf16* sVl = (__bf16*)(smem + 18432);
  __bf16* sAh = (__bf16*)(smem + 36864);        // [64][72]
  __bf16* sAl = (__bf16*)(smem + 46080);
  const int tid = threadIdx.x;
  const int d0 = blockIdx.x << 7;
  const int n0 = blockIdx.y << 6;
  const int bp = blockIdx.z, b = bp >> 1;
  const int w = tid >> 6, q = (tid >> 4) & 3, ln = tid & 15;
  const __bf16* vhp = vth + (((size_t)bp * 16384 + d0) << 8);
  const __bf16* vlp = vtl + (((size_t)bp * 16384 + d0) << 8);
  float* op = out + (size_t)bp * PLANE;

  f32x4 zero = {0.f, 0.f, 0.f, 0.f};
  f32x4 acc[2][4];
#pragma unroll
  for (int mt = 0; mt < 2; ++mt)
#pragma unroll
    for (int nt = 0; nt < 4; ++nt) acc[mt][nt] = zero;

  for (int m0 = 0; m0 < 256; m0 += 64) {
    // stage V tile [128][64] hi/lo (bf16, straight copy, b128 in/out)
#pragma unroll
    for (int r = 0; r < 4; ++r) {
      int u = tid + (r << 8);
      int dl = u >> 3, g = (u & 7) << 3;
      *(bf16x8*)&sVh[dl * 72 + g] = *(const bf16x8*)&vhp[dl * 256 + m0 + g];
      *(bf16x8*)&sVl[dl * 72 + g] = *(const bf16x8*)&vlp[dl * 256 + m0 + g];
    }
    // stage A tile [64][64] fp32 -> split hi/lo
#pragma unroll
    for (int r = 0; r < 4; ++r) {
      int u = tid + (r << 8);
      int mj = (u & 15) << 2, nl = u >> 4;
      float4 v4 = *(const float4*)&am[(b << 16) + ((n0 + nl) << 8) + m0 + mj];
      float vv[4] = {v4.x, v4.y, v4.z, v4.w};
      bf16x4v h, l;
#pragma unroll
      for (int e = 0; e < 4; ++e) {
        __bf16 hh = (__bf16)vv[e];
        h[e] = hh; l[e] = (__bf16)(vv[e] - (float)hh);
      }
      *(bf16x4v*)&sAh[nl * 72 + mj] = h;
      *(bf16x4v*)&sAl[nl * 72 + mj] = l;
    }
    __syncthreads();

#pragma unroll
    for (int ks = 0; ks < 2; ++ks) {
      bf16x8 vhf[2], vlf[2], ahf[4], alf[4];
#pragma unroll
      for (int mt = 0; mt < 2; ++mt) {
        int off = (w * 32 + mt * 16 + ln) * 72 + ks * 32 + q * 8;
        vhf[mt] = *(const bf16x8*)&sVh[off];
        vlf[mt] = *(const bf16x8*)&sVl[off];
      }
#pragma unroll
      for (int nt = 0; nt < 4; ++nt) {
        int off = (nt * 16 + ln) * 72 + ks * 32 + q * 8;
        ahf[nt] = *(const bf16x8*)&sAh[off];
        alf[nt] = *(const bf16x8*)&sAl[off];
      }
#pragma unroll
      for (int mt = 0; mt < 2; ++mt)
#pragma unroll
        for (int nt = 0; nt < 4; ++nt) {
          f32x4 a = acc[mt][nt];
          a = mfma16(vhf[mt], ahf[nt], a);
          a = mfma16(vhf[mt], alf[nt], a);
          a = mfma16(vlf[mt], ahf[nt], a);
          acc[mt][nt] = a;
        }
    }
    __syncthreads();
  }

  if (!freq) {
    // time phase: direct [d][n] store (phase 0, no accumulate)
#pragma unroll
    for (int mt = 0; mt < 2; ++mt)
#pragma unroll
      for (int nt = 0; nt < 4; ++nt)
#pragma unroll
        for (int r = 0; r < 4; ++r) {
          int row = d0 + w * 32 + mt * 16 + q * 4 + r;
          op[(size_t)row * 256 + n0 + nt * 16 + ln] = acc[mt][nt][r];
        }
  } else {
    // freq phase: LDS transpose so global RMW stays float4 along t
    float* sO = (float*)smem;   // [128][65] = 33280 B (fits in smem)
#pragma unroll
    for (int mt = 0; mt < 2; ++mt)
#pragma unroll
      for (int nt = 0; nt < 4; ++nt)
#pragma unroll
        for (int r = 0; r < 4; ++r)
          sO[(w * 32 + mt * 16 + q * 4 + r) * 65 + nt * 16 + ln] = acc[mt][nt][r];
    __syncthreads();
    const int c = d0 >> 8, t0 = d0 & 255;
    const int dl = (tid & 31) << 2, nb = tid >> 5;
#pragma unroll
    for (int r = 0; r < 8; ++r) {
      int n = nb + (r << 3);
      float4 wv = make_float4(sO[(dl + 0) * 65 + n], sO[(dl + 1) * 65 + n],
                              sO[(dl + 2) * 65 + n], sO[(dl + 3) * 65 + n]);
      size_t addr = (size_t)c * SS + (size_t)(n0 + n) * 256 + t0 + dl;
      float4 o = *(float4*)&op[addr];
      wv.x += o.x; wv.y += o.y; wv.z += o.z; wv.w += o.w;
      *(float4*)&op[addr] = wv;
    }
  }
}

extern "C" void kernel_launch(void* const* d_in, const int* in_sizes, int n_in,
                              void* d_out, int out_size, void* d_ws, size_t ws_size,
                              hipStream_t stream) {
  const float* P    = (const float*)d_in[0];
  const float* Q    = (const float*)d_in[1];
  const float* W    = (const float*)d_in[2];
  const float* bias = (const float*)d_in[3];
  const float* g    = (const float*)d_in[4];
  const float* beta = (const float*)d_in[5];
  float* out = (float*)d_out;
  float* ws  = (float*)d_ws;

  float* Y0    = ws;
  float* Y1    = Y0 + TEN_ELEMS;
  float* Y2    = Y1 + TEN_ELEMS;
  float* SR    = Y2 + TEN_ELEMS;
  float* SI    = SR + 131072;
  float* AM    = SI + 131072;
  float* BUCK  = AM + 131072;             // 64 * 768 = 49152 floats
  float* SCALE = BUCK + NBUCKET * 768;    // 384
  float* SHIFT = SCALE + 384;             // 384

  // V bf16 hi/lo live in Y0's slot (Y0 is dead after score_mfma):
  // 16777216 bf16 each = 32 MiB + 32 MiB, fits in Y0's 64 MiB exactly.
  __bf16* VTh = (__bf16*)Y0;
  __bf16* VTl = VTh + TEN_ELEMS;

  for (int phase = 0; phase < 2; ++phase) {
    int j0 = phase * 3;
    int freq = phase;
    hipMemsetAsync(BUCK, 0, NBUCKET * 768 * sizeof(float), stream);
    cconv_mfma<<<dim3(1024, 2), 256, 0, stream>>>(
        Q, W + (size_t)j0 * 8192, bias + j0 * 128, Y0, BUCK);
    cconv_mfma<<<dim3(1024, 2), 256, 0, stream>>>(
        P, W + (size_t)(j0 + 1) * 8192, bias + (j0 + 1) * 128, Y1, BUCK + 256);
    cconv_mfma<<<dim3(1024, 2), 256, 0, stream>>>(
        P, W + (size_t)(j0 + 2) * 8192, bias + (j0 + 2) * 128, Y2, BUCK + 512);
    bn_finalize<<<2, 256, 0, stream>>>(BUCK, g, beta, j0 * 128, SCALE, SHIFT);
    bn_apply<<<49152, 256, 0, stream>>>(Y0, SCALE, SHIFT);   // covers Y0..Y2
    hipMemsetAsync(SR, 0, 2 * 131072 * sizeof(float), stream);
    score_mfma<<<dim3(8, 32, 2), 256, 0, stream>>>(Y0, Y1, SR, SI, freq);
    softmax_kernel<<<512, 256, 0, stream>>>(SR, SI, AM);
    if (!freq)
      vt_convert<<<16384, 256, 0, stream>>>(Y2, VTh, VTl);
    else
      vt_transpose<<<dim3(16, 256), 256, 0, stream>>>(Y2, VTh, VTl);
    av_mfma<<<dim3(128, 4, 4), 256, 0, stream>>>(AM, VTh, VTl, out, freq);
  }
}

// Round 3
// 803.210 us; speedup vs baseline: 1.2308x; 1.0766x over previous
//
#include <hip/hip_runtime.h>
#include <math.h>

#define SS 65536               // F*T
#define PLANE 4194304          // CC*SS floats per (b,part)
#define TEN_ELEMS 16777216     // 2*2*CC*SS floats per tensor
#define NBUCKET 64

typedef __bf16 bf16x8 __attribute__((ext_vector_type(8)));
typedef __bf16 bf16x4v __attribute__((ext_vector_type(4)));
typedef float  f32x4  __attribute__((ext_vector_type(4)));

__device__ inline f32x4 mfma16(bf16x8 a, bf16x8 b, f32x4 c) {
  return __builtin_amdgcn_mfma_f32_16x16x32_bf16(a, b, c, 0, 0, 0);
}
__device__ inline bf16x8 neg8(bf16x8 v) {
  union { bf16x8 b; unsigned u[4]; } t; t.b = v;
#pragma unroll
  for (int i = 0; i < 4; ++i) t.u[i] ^= 0x80008000u;
  return t.b;
}
__device__ inline float bnlrelu(float v, float sc, float sh) {
  float t = fmaf(v, sc, sh);
  return t > 0.f ? t : 0.01f * t;
}

// swizzled element offset of 16B-granule g within row r (rows of 40 elems)
__device__ inline int swz(int r, int g) {
  return r * 40 + (((g ^ (r >> 2) ^ (r >> 4)) & 3) << 3);
}

// ============ complex 1x1 conv (split-bf16 MFMA) + bias + BN stats ==========
__global__ __launch_bounds__(256) void cconv_mfma(
    const float* __restrict__ x, const float* __restrict__ Wj,
    const float* __restrict__ bias, float* __restrict__ y,
    float* __restrict__ part)
{
  __shared__ __align__(16) __bf16 sBh[64 * 136];   // [s][pc] hi
  __shared__ __align__(16) __bf16 sBl[64 * 136];   // [s][pc] lo
  const int tid = threadIdx.x;
  const int b = blockIdx.y;
  const int s0 = blockIdx.x << 6;
  const int bkt = (blockIdx.x & (NBUCKET - 1)) * 768;
  const int w = tid >> 6, q = (tid >> 4) & 3, ln = tid & 15;

  bf16x8 ah[2][4], al[2][4];
#pragma unroll
  for (int mt = 0; mt < 2; ++mt) {
    int row = w * 32 + mt * 16 + ln;
    int po = row >> 6, co = row & 63;
#pragma unroll
    for (int ks = 0; ks < 4; ++ks) {
      bf16x8 vh, vl;
#pragma unroll
      for (int j = 0; j < 8; ++j) {
        int k = ks * 32 + q * 8 + j;
        int pi = k >> 6, c = k & 63;
        float v = Wj[((po ^ pi) << 12) + co * 64 + c];
        if (po == 0 && pi == 1) v = -v;
        __bf16 h = (__bf16)v;
        vh[j] = h;
        vl[j] = (__bf16)(v - (float)h);
      }
      ah[mt][ks] = vh; al[mt][ks] = vl;
    }
  }

#pragma unroll
  for (int ph = 0; ph < 2; ++ph) {
    int pc = ph * 64 + (tid & 63);
    const float* rowp = x + (size_t)(b * 128 + pc) * SS + s0;
#pragma unroll
    for (int sh2 = 0; sh2 < 2; ++sh2)
#pragma unroll
      for (int sc2 = 0; sc2 < 2; ++sc2) {
        int sl = ((tid >> 6) << 3) + sh2 * 32 + sc2 * 4;
        float4 rd = *(const float4*)&rowp[sl];
        float vv[4] = {rd.x, rd.y, rd.z, rd.w};
#pragma unroll
        for (int e = 0; e < 4; ++e) {
          __bf16 h = (__bf16)vv[e];
          sBh[(sl + e) * 136 + pc] = h;
          sBl[(sl + e) * 136 + pc] = (__bf16)(vv[e] - (float)h);
        }
      }
  }
  __syncthreads();

  f32x4 zero = {0.f, 0.f, 0.f, 0.f};
  f32x4 acc[2][4];
#pragma unroll
  for (int mt = 0; mt < 2; ++mt)
#pragma unroll
    for (int nt = 0; nt < 4; ++nt) acc[mt][nt] = zero;

#pragma unroll
  for (int ks = 0; ks < 4; ++ks) {
    bf16x8 bh[4], bl[4];
#pragma unroll
    for (int nt = 0; nt < 4; ++nt) {
      int off = (nt * 16 + ln) * 136 + ks * 32 + q * 8;
      bh[nt] = *(const bf16x8*)&sBh[off];
      bl[nt] = *(const bf16x8*)&sBl[off];
    }
#pragma unroll
    for (int mt = 0; mt < 2; ++mt)
#pragma unroll
      for (int nt = 0; nt < 4; ++nt) {
        acc[mt][nt] = mfma16(ah[mt][ks], bh[nt], acc[mt][nt]);
        acc[mt][nt] = mfma16(ah[mt][ks], bl[nt], acc[mt][nt]);
        acc[mt][nt] = mfma16(al[mt][ks], bh[nt], acc[mt][nt]);
      }
  }

#pragma unroll
  for (int mt = 0; mt < 2; ++mt) {
    int rowb = w * 32 + mt * 16 + q * 4;
#pragma unroll
    for (int r = 0; r < 4; ++r) {
      float bv = bias[rowb + r];
      float vs[4];
      float sm = 0.f, sq = 0.f;
#pragma unroll
      for (int nt = 0; nt < 4; ++nt) {
        float v = acc[mt][nt][r] + bv;
        vs[nt] = v; sm += v; sq += v * v;
      }
#pragma unroll
      for (int off = 1; off < 16; off <<= 1) {
        sm += __shfl_xor(sm, off, 64);
        sq += __shfl_xor(sq, off, 64);
      }
      if (ln == 0) {
        atomicAdd(&part[bkt + (rowb + r) * 2 + 0], sm);
        atomicAdd(&part[bkt + (rowb + r) * 2 + 1], sq);
      }
#pragma unroll
      for (int nt = 0; nt < 4; ++nt)
        y[(size_t)((b << 7) + rowb + r) * SS + s0 + nt * 16 + ln] = vs[nt];
    }
  }
}

// ---------------- BN finalize (reduce buckets) ------------------------------
__global__ void bn_finalize(const float* __restrict__ buckets,
                            const float* __restrict__ g,
                            const float* __restrict__ beta, int goff,
                            float* __restrict__ scale, float* __restrict__ shift)
{
  int i = blockIdx.x * 256 + threadIdx.x;   // 0..383 = [role3][p][co]
  if (i >= 384) return;
  int role = i >> 7, pc = i & 127;
  float sm = 0.f, sq = 0.f;
  const float* bp = buckets + role * 256 + pc * 2;
#pragma unroll 4
  for (int k = 0; k < NBUCKET; ++k) {
    sm += bp[k * 768 + 0];
    sq += bp[k * 768 + 1];
  }
  const float inv = 1.f / 131072.f;
  float mu = sm * inv;
  float var = sq * inv - mu * mu;
  float istd = rsqrtf(var + 1e-5f);
  float gg = g[goff + role * 128 + pc];
  float bb = beta[goff + role * 128 + pc];
  float sc = gg * istd;
  scale[i] = sc;
  shift[i] = bb - mu * sc;
}

// ============ complex scores (split-bf16 MFMA, split-K, atomics) ============
// BN + leaky relu fused into staging (scale/shift: Q=idx p*64+c, K=128+...)
__global__ __launch_bounds__(256) void score_mfma(
    const float* __restrict__ qg, const float* __restrict__ kg,
    const float* __restrict__ scale, const float* __restrict__ shift,
    float* __restrict__ SR, float* __restrict__ SI, int freq)
{
  __shared__ __align__(16) __bf16 sQh[2 * 128 * 40], sQl[2 * 128 * 40];
  __shared__ __align__(16) __bf16 sKh[2 * 64 * 40],  sKl[2 * 64 * 40];
  const int tid = threadIdx.x;
  const int sid = blockIdx.x + (blockIdx.y << 3) + (blockIdx.z << 8);
  const int kk = sid & 7, tt = sid >> 3;
  const int n0 = (kk & 1) << 7;
  const int b  = (kk >> 1) & 1;
  const int m0 = (tt & 3) << 6;
  const int d0 = (((kk >> 2) << 4) + (tt >> 2)) << 9;   // 32 splits x 512
  const int w = tid >> 6, q4 = (tid >> 4) & 3, ln = tid & 15;
  const float* qp = qg + (size_t)b * 2 * PLANE;
  const float* kp = kg + (size_t)b * 2 * PLANE;

  f32x4 zero = {0.f, 0.f, 0.f, 0.f};
  f32x4 accr[2][4], acci[2][4];
#pragma unroll
  for (int st = 0; st < 2; ++st)
#pragma unroll
    for (int mt = 0; mt < 4; ++mt) { accr[st][mt] = zero; acci[st][mt] = zero; }

  for (int ch = 0; ch < 16; ++ch) {
    const int dd = d0 + ch * 32;
    const int cc = dd >> 8;       // BN channel, uniform for this chunk
    if (!freq) {
#pragma unroll
      for (int r = 0; r < 8; ++r) {
        int u = tid + 256 * r;
        int tok4 = u & 31, dl = (u >> 5) & 31, p = u >> 10;
        float sc = scale[p * 64 + cc], sh = shift[p * 64 + cc];
        float4 v4 = *(const float4*)&qp[(size_t)p * PLANE +
                                        (size_t)(dd + dl) * 256 + n0 + tok4 * 4];
        float vv[4] = {v4.x, v4.y, v4.z, v4.w};
#pragma unroll
        for (int e = 0; e < 4; ++e) {
          float v = bnlrelu(vv[e], sc, sh);
          int row = p * 128 + tok4 * 4 + e;
          int off = swz(row, dl >> 3) + (dl & 7);
          __bf16 h = (__bf16)v;
          sQh[off] = h;
          sQl[off] = (__bf16)(v - (float)h);
        }
      }
#pragma unroll
      for (int r = 0; r < 4; ++r) {
        int u = tid + 256 * r;
        int tok4 = u & 15, dl = (u >> 4) & 31, p = u >> 9;
        float sc = scale[128 + p * 64 + cc], sh = shift[128 + p * 64 + cc];
        float4 v4 = *(const float4*)&kp[(size_t)p * PLANE +
                                        (size_t)(dd + dl) * 256 + m0 + tok4 * 4];
        float vv[4] = {v4.x, v4.y, v4.z, v4.w};
#pragma unroll
        for (int e = 0; e < 4; ++e) {
          float v = bnlrelu(vv[e], sc, sh);
          int row = p * 64 + tok4 * 4 + e;
          int off = swz(row, dl >> 3) + (dl & 7);
          __bf16 h = (__bf16)v;
          sKh[off] = h;
          sKl[off] = (__bf16)(v - (float)h);
        }
      }
    } else {
      const int c = dd >> 8, t0c = dd & 255;
#pragma unroll
      for (int r = 0; r < 8; ++r) {
        int u = tid + 256 * r;
        int dc = u & 7, tok = (u >> 3) & 127, p = u >> 10;
        float sc = scale[p * 64 + c], sh = shift[p * 64 + c];
        float4 v4 = *(const float4*)&qp[(size_t)p * PLANE + (size_t)c * 65536 +
                                        t0c + dc * 4 + (size_t)(n0 + tok) * 256];
        float vv[4] = {v4.x, v4.y, v4.z, v4.w};
        bf16x4v hv, lv;
#pragma unroll
        for (int e = 0; e < 4; ++e) {
          float v = bnlrelu(vv[e], sc, sh);
          __bf16 h = (__bf16)v;
          hv[e] = h; lv[e] = (__bf16)(v - (float)h);
        }
        int row = p * 128 + tok;
        int off = swz(row, dc >> 1) + ((dc & 1) << 2);
        *(bf16x4v*)&sQh[off] = hv;
        *(bf16x4v*)&sQl[off] = lv;
      }
#pragma unroll
      for (int r = 0; r < 4; ++r) {
        int u = tid + 256 * r;
        int dc = u & 7, tok = (u >> 3) & 63, p = u >> 9;
        float sc = scale[128 + p * 64 + c], sh = shift[128 + p * 64 + c];
        float4 v4 = *(const float4*)&kp[(size_t)p * PLANE + (size_t)c * 65536 +
                                        t0c + dc * 4 + (size_t)(m0 + tok) * 256];
        float vv[4] = {v4.x, v4.y, v4.z, v4.w};
        bf16x4v hv, lv;
#pragma unroll
        for (int e = 0; e < 4; ++e) {
          float v = bnlrelu(vv[e], sc, sh);
          __bf16 h = (__bf16)v;
          hv[e] = h; lv[e] = (__bf16)(v - (float)h);
        }
        int row = p * 64 + tok;
        int off = swz(row, dc >> 1) + ((dc & 1) << 2);
        *(bf16x4v*)&sKh[off] = hv;
        *(bf16x4v*)&sKl[off] = lv;
      }
    }
    __syncthreads();

    bf16x8 qh[2][2], ql2[2][2], nqh[2], nql[2];
#pragma unroll
    for (int st = 0; st < 2; ++st) {
      int tokn = w * 32 + st * 16 + ln;
#pragma unroll
      for (int p = 0; p < 2; ++p) {
        int off = swz(p * 128 + tokn, q4);
        qh[st][p]  = *(const bf16x8*)&sQh[off];
        ql2[st][p] = *(const bf16x8*)&sQl[off];
      }
      nqh[st] = neg8(qh[st][0]);
      nql[st] = neg8(ql2[st][0]);
    }
#pragma unroll
    for (int mt = 0; mt < 4; ++mt) {
      int tk = mt * 16 + ln;
      int offr = swz(tk, q4), offi = swz(64 + tk, q4);
      bf16x8 krh = *(const bf16x8*)&sKh[offr];
      bf16x8 krl = *(const bf16x8*)&sKl[offr];
      bf16x8 kih = *(const bf16x8*)&sKh[offi];
      bf16x8 kil = *(const bf16x8*)&sKl[offi];
#pragma unroll
      for (int st = 0; st < 2; ++st) {
        f32x4 ar = accr[st][mt], ai = acci[st][mt];
        ar = mfma16(qh[st][0], krh, ar);
        ar = mfma16(qh[st][0], krl, ar);
        ar = mfma16(ql2[st][0], krh, ar);
        ar = mfma16(qh[st][1], kih, ar);
        ar = mfma16(qh[st][1], kil, ar);
        ar = mfma16(ql2[st][1], kih, ar);
        ai = mfma16(qh[st][1], krh, ai);
        ai = mfma16(qh[st][1], krl, ai);
        ai = mfma16(ql2[st][1], krh, ai);
        ai = mfma16(nqh[st], kih, ai);
        ai = mfma16(nqh[st], kil, ai);
        ai = mfma16(nql[st], kih, ai);
        accr[st][mt] = ar; acci[st][mt] = ai;
      }
    }
    __syncthreads();
  }

#pragma unroll
  for (int st = 0; st < 2; ++st)
#pragma unroll
    for (int mt = 0; mt < 4; ++mt)
#pragma unroll
      for (int r = 0; r < 4; ++r) {
        int n = n0 + w * 32 + st * 16 + q4 * 4 + r;
        int m = m0 + mt * 16 + ln;
        int idx = (b << 16) + (n << 8) + m;
        atomicAdd(&SR[idx], accr[st][mt][r]);
        atomicAdd(&SI[idx], acci[st][mt][r]);
      }
}

// ---------------- softmax over n (axis=1), per (b,m) column -----------------
__global__ __launch_bounds__(256) void softmax_kernel(
    const float* __restrict__ sr, const float* __restrict__ si,
    float* __restrict__ am)
{
  const int m = blockIdx.x & 255;
  const int b = blockIdx.x >> 8;
  const int n = threadIdx.x;
  const int idx = (b << 16) + (n << 8) + m;
  float vr = sr[idx], vi = si[idx];
  float mag = sqrtf(vr * vr + vi * vi);
  __shared__ float wmax[4];
  __shared__ float wsum[4];
  float mx = mag;
  #pragma unroll
  for (int off = 1; off < 64; off <<= 1)
    mx = fmaxf(mx, __shfl_xor(mx, off, 64));
  if ((threadIdx.x & 63) == 0) wmax[threadIdx.x >> 6] = mx;
  __syncthreads();
  mx = fmaxf(fmaxf(wmax[0], wmax[1]), fmaxf(wmax[2], wmax[3]));
  float e = expf(mag - mx);
  float sm = e;
  #pragma unroll
  for (int off = 1; off < 64; off <<= 1)
    sm += __shfl_xor(sm, off, 64);
  if ((threadIdx.x & 63) == 0) wsum[threadIdx.x >> 6] = sm;
  __syncthreads();
  float tot = wsum[0] + wsum[1] + wsum[2] + wsum[3];
  am[idx] = e / tot;
}

// ======== V prep: raw V -> BN+leaky -> bf16 hi/lo, uniform [d][m] layout ====
// time phase: [d][m] already linear -> straight convert (V role = scale+256)
__global__ __launch_bounds__(256) void vt_convert(
    const float* __restrict__ y2, const float* __restrict__ scale,
    const float* __restrict__ shift, __bf16* __restrict__ vh,
    __bf16* __restrict__ vl)
{
  size_t i = ((size_t)blockIdx.x * 256 + threadIdx.x) << 2;
  int idx = 256 + (int)((i >> 16) & 127);
  float sc = scale[idx], sh = shift[idx];
  float4 v = *(const float4*)&y2[i];
  float vv[4] = {v.x, v.y, v.z, v.w};
  bf16x4v h, l;
#pragma unroll
  for (int e = 0; e < 4; ++e) {
    float t = bnlrelu(vv[e], sc, sh);
    __bf16 hh = (__bf16)t;
    h[e] = hh; l[e] = (__bf16)(t - (float)hh);
  }
  *(bf16x4v*)&vh[i] = h;
  *(bf16x4v*)&vl[i] = l;
}

// freq phase: V[d=c*256+t][m=f] = Y2[c][f*256+t] -> 64x64 LDS tile transpose
__global__ __launch_bounds__(256) void vt_transpose(
    const float* __restrict__ y2, const float* __restrict__ scale,
    const float* __restrict__ shift, __bf16* __restrict__ vh,
    __bf16* __restrict__ vl)
{
  __shared__ float sT[64 * 65];
  const int tid = threadIdx.x;
  const int bpc = blockIdx.y;           // bp*64 + c
  const int bp = bpc >> 6, c = bpc & 63;
  const int f0 = (blockIdx.x >> 2) << 6, t0 = (blockIdx.x & 3) << 6;
  const float sc = scale[256 + (bp & 1) * 64 + c];
  const float sh = shift[256 + (bp & 1) * 64 + c];
  const float* src = y2 + (size_t)bp * PLANE + (size_t)c * SS;
#pragma unroll
  for (int r = 0; r < 4; ++r) {
    int fl = (tid >> 4) + (r << 4);
    int tl = (tid & 15) << 2;
    float4 v = *(const float4*)&src[(f0 + fl) * 256 + t0 + tl];
    sT[fl * 65 + tl + 0] = bnlrelu(v.x, sc, sh);
    sT[fl * 65 + tl + 1] = bnlrelu(v.y, sc, sh);
    sT[fl * 65 + tl + 2] = bnlrelu(v.z, sc, sh);
    sT[fl * 65 + tl + 3] = bnlrelu(v.w, sc, sh);
  }
  __syncthreads();
  __bf16* dsth = vh + (((size_t)bp * 16384 + c * 256) << 8);
  __bf16* dstl = vl + (((size_t)bp * 16384 + c * 256) << 8);
#pragma unroll
  for (int r = 0; r < 4; ++r) {
    int tl = (tid >> 4) + (r << 4);
    int fl = (tid & 15) << 2;
    bf16x4v h, l;
#pragma unroll
    for (int e = 0; e < 4; ++e) {
      float vv = sT[(fl + e) * 65 + tl];
      __bf16 hh = (__bf16)vv;
      h[e] = hh; l[e] = (__bf16)(vv - (float)hh);
    }
    *(bf16x4v*)&dsth[(size_t)(t0 + tl) * 256 + f0 + fl] = h;
    *(bf16x4v*)&dstl[(size_t)(t0 + tl) * 256 + f0 + fl] = l;
  }
}

// ======== out[d,n] = sum_m A[n,m] * V[d,m] via split-bf16 MFMA ==============
__global__ __launch_bounds__(256) void av_mfma(
    const float* __restrict__ am, const __bf16* __restrict__ vth,
    const __bf16* __restrict__ vtl, float* __restrict__ out, int freq)
{
  __shared__ __align__(16) char smem[55296];
  __bf16* sVh = (__bf16*)smem;                  // [128][72]
  __bf16* sVl = (__bf16*)(smem + 18432);
  __bf16* sAh = (__bf16*)(smem + 36864);        // [64][72]
  __bf16* sAl = (__bf16*)(smem + 46080);
  const int tid = threadIdx.x;
  const int d0 = blockIdx.x << 7;
  const int n0 = blockIdx.y << 6;
  const int bp = blockIdx.z, b = bp >> 1;
  const int w = tid >> 6, q = (tid >> 4) & 3, ln = tid & 15;
  const __bf16* vhp = vth + (((size_t)bp * 16384 + d0) << 8);
  const __bf16* vlp = vtl + (((size_t)bp * 16384 + d0) << 8);
  float* op = out + (size_t)bp * PLANE;

  f32x4 zero = {0.f, 0.f, 0.f, 0.f};
  f32x4 acc[2][4];
#pragma unroll
  for (int mt = 0; mt < 2; ++mt)
#pragma unroll
    for (int nt = 0; nt < 4; ++nt) acc[mt][nt] = zero;

  for (int m0 = 0; m0 < 256; m0 += 64) {
#pragma unroll
    for (int r = 0; r < 4; ++r) {
      int u = tid + (r << 8);
      int dl = u >> 3, g = (u & 7) << 3;
      *(bf16x8*)&sVh[dl * 72 + g] = *(const bf16x8*)&vhp[dl * 256 + m0 + g];
      *(bf16x8*)&sVl[dl * 72 + g] = *(const bf16x8*)&vlp[dl * 256 + m0 + g];
    }
#pragma unroll
    for (int r = 0; r < 4; ++r) {
      int u = tid + (r << 8);
      int mj = (u & 15) << 2, nl = u >> 4;
      float4 v4 = *(const float4*)&am[(b << 16) + ((n0 + nl) << 8) + m0 + mj];
      float vv[4] = {v4.x, v4.y, v4.z, v4.w};
      bf16x4v h, l;
#pragma unroll
      for (int e = 0; e < 4; ++e) {
        __bf16 hh = (__bf16)vv[e];
        h[e] = hh; l[e] = (__bf16)(vv[e] - (float)hh);
      }
      *(bf16x4v*)&sAh[nl * 72 + mj] = h;
      *(bf16x4v*)&sAl[nl * 72 + mj] = l;
    }
    __syncthreads();

#pragma unroll
    for (int ks = 0; ks < 2; ++ks) {
      bf16x8 vhf[2], vlf[2], ahf[4], alf[4];
#pragma unroll
      for (int mt = 0; mt < 2; ++mt) {
        int off = (w * 32 + mt * 16 + ln) * 72 + ks * 32 + q * 8;
        vhf[mt] = *(const bf16x8*)&sVh[off];
        vlf[mt] = *(const bf16x8*)&sVl[off];
      }
#pragma unroll
      for (int nt = 0; nt < 4; ++nt) {
        int off = (nt * 16 + ln) * 72 + ks * 32 + q * 8;
        ahf[nt] = *(const bf16x8*)&sAh[off];
        alf[nt] = *(const bf16x8*)&sAl[off];
      }
#pragma unroll
      for (int mt = 0; mt < 2; ++mt)
#pragma unroll
        for (int nt = 0; nt < 4; ++nt) {
          f32x4 a = acc[mt][nt];
          a = mfma16(vhf[mt], ahf[nt], a);
          a = mfma16(vhf[mt], alf[nt], a);
          a = mfma16(vlf[mt], ahf[nt], a);
          acc[mt][nt] = a;
        }
    }
    __syncthreads();
  }

  if (!freq) {
#pragma unroll
    for (int mt = 0; mt < 2; ++mt)
#pragma unroll
      for (int nt = 0; nt < 4; ++nt)
#pragma unroll
        for (int r = 0; r < 4; ++r) {
          int row = d0 + w * 32 + mt * 16 + q * 4 + r;
          op[(size_t)row * 256 + n0 + nt * 16 + ln] = acc[mt][nt][r];
        }
  } else {
    float* sO = (float*)smem;   // [128][65]
#pragma unroll
    for (int mt = 0; mt < 2; ++mt)
#pragma unroll
      for (int nt = 0; nt < 4; ++nt)
#pragma unroll
        for (int r = 0; r < 4; ++r)
          sO[(w * 32 + mt * 16 + q * 4 + r) * 65 + nt * 16 + ln] = acc[mt][nt][r];
    __syncthreads();
    const int c = d0 >> 8, t0 = d0 & 255;
    const int dl = (tid & 31) << 2, nb = tid >> 5;
#pragma unroll
    for (int r = 0; r < 8; ++r) {
      int n = nb + (r << 3);
      float4 wv = make_float4(sO[(dl + 0) * 65 + n], sO[(dl + 1) * 65 + n],
                              sO[(dl + 2) * 65 + n], sO[(dl + 3) * 65 + n]);
      size_t addr = (size_t)c * SS + (size_t)(n0 + n) * 256 + t0 + dl;
      float4 o = *(float4*)&op[addr];
      wv.x += o.x; wv.y += o.y; wv.z += o.z; wv.w += o.w;
      *(float4*)&op[addr] = wv;
    }
  }
}

extern "C" void kernel_launch(void* const* d_in, const int* in_sizes, int n_in,
                              void* d_out, int out_size, void* d_ws, size_t ws_size,
                              hipStream_t stream) {
  const float* P    = (const float*)d_in[0];
  const float* Q    = (const float*)d_in[1];
  const float* W    = (const float*)d_in[2];
  const float* bias = (const float*)d_in[3];
  const float* g    = (const float*)d_in[4];
  const float* beta = (const float*)d_in[5];
  float* out = (float*)d_out;
  float* ws  = (float*)d_ws;

  float* Y0    = ws;
  float* Y1    = Y0 + TEN_ELEMS;
  float* Y2    = Y1 + TEN_ELEMS;
  float* SR    = Y2 + TEN_ELEMS;
  float* SI    = SR + 131072;
  float* AM    = SI + 131072;
  float* BUCK  = AM + 131072;             // 64 * 768 = 49152 floats
  float* SCALE = BUCK + NBUCKET * 768;    // 384
  float* SHIFT = SCALE + 384;             // 384

  // V bf16 hi/lo live in Y0's slot (Y0 is dead after score_mfma)
  __bf16* VTh = (__bf16*)Y0;
  __bf16* VTl = VTh + TEN_ELEMS;

  for (int phase = 0; phase < 2; ++phase) {
    int j0 = phase * 3;
    int freq = phase;
    hipMemsetAsync(BUCK, 0, NBUCKET * 768 * sizeof(float), stream);
    cconv_mfma<<<dim3(1024, 2), 256, 0, stream>>>(
        Q, W + (size_t)j0 * 8192, bias + j0 * 128, Y0, BUCK);
    cconv_mfma<<<dim3(1024, 2), 256, 0, stream>>>(
        P, W + (size_t)(j0 + 1) * 8192, bias + (j0 + 1) * 128, Y1, BUCK + 256);
    cconv_mfma<<<dim3(1024, 2), 256, 0, stream>>>(
        P, W + (size_t)(j0 + 2) * 8192, bias + (j0 + 2) * 128, Y2, BUCK + 512);
    bn_finalize<<<2, 256, 0, stream>>>(BUCK, g, beta, j0 * 128, SCALE, SHIFT);
    hipMemsetAsync(SR, 0, 2 * 131072 * sizeof(float), stream);
    score_mfma<<<dim3(8, 32, 2), 256, 0, stream>>>(Y0, Y1, SCALE, SHIFT,
                                                   SR, SI, freq);
    softmax_kernel<<<512, 256, 0, stream>>>(SR, SI, AM);
    if (!freq)
      vt_convert<<<16384, 256, 0, stream>>>(Y2, SCALE, SHIFT, VTh, VTl);
    else
      vt_transpose<<<dim3(16, 256), 256, 0, stream>>>(Y2, SCALE, SHIFT, VTh, VTl);
    av_mfma<<<dim3(128, 4, 4), 256, 0, stream>>>(AM, VTh, VTl, out, freq);
  }
}